// Round 7
// baseline (37.085 us; speedup 1.0000x reference)
//
#include <hip/hip_runtime.h>
#include <stdint.h>

// Problem constants (fixed by setup_inputs)
#define BB 64
#define TT 8192
#define VV 50257
// max_phrase_len = 32, pad_token_id = 0 (hardcoded)

#define NBMW 1571                      // ceil(VV/32) bitmap words per table
// Workspace layout (byte offsets)
#define WS_BMP   4096                  // uint32[1600] punct bitmap
#define WS_BMA   (4096 + 6400)         // uint32[1600] abbr bitmap

__device__ __forceinline__ unsigned long long bitsBelow(int e) {  // bits 0..e-1, e in [0,64]
    return (e >= 64) ? ~0ULL : ((1ULL << e) - 1ULL);
}

__device__ __forceinline__ bool lut(const void* tbl, int flag, int idx) {
    if (flag == 2) return ((const float*)tbl)[idx]   != 0.0f;
    if (flag == 1) return ((const uint8_t*)tbl)[idx] != 0;
    return ((const int*)tbl)[idx] != 0;
}

// ---------------------------------------------------------------------------
// bitmap_kernel: compress both bool tables to bitmaps (6.3KB each) so the hot
// kernel's tests are L1-resident bit probes instead of L2 gathers.
// Per-block 4KB dtype probe (0=int32, 1=uint8, 2=float32): f32 words have
// high bytes set (1.0f=0x3F800000); uint8 packs 4 bools/word (word>1).
// Grid: 2*197 blocks x 256 threads; one entry/thread; 64-lane ballot -> u64
// store covering two uint32 bitmap words (i%64==0 => word index even).
// ---------------------------------------------------------------------------
__global__ __launch_bounds__(256) void bitmap_kernel(
        const void* __restrict__ punct, const void* __restrict__ abbr,
        uint32_t* __restrict__ bmP, uint32_t* __restrict__ bmA) {
    __shared__ int sFlag;
    if (threadIdx.x == 0) sFlag = 0;
    __syncthreads();
    {
        const uint32_t* w = (const uint32_t*)punct;
        bool byteGT1 = false, wordGT1 = false;
#pragma unroll
        for (int j = 0; j < 4; ++j) {
            uint32_t x = w[threadIdx.x * 4 + j];
            byteGT1 |= (x & 0xFEFEFEFEu) != 0u;
            wordGT1 |= (x > 1u);
        }
        int local = (byteGT1 ? 2 : 0) | (wordGT1 ? 1 : 0);
        if (local) atomicOr(&sFlag, local);
    }
    __syncthreads();
    int fl = sFlag;
    int flag = (fl & 2) ? 2 : (fl & 1);

    int nb = (int)gridDim.x >> 1;            // blocks per table
    int isAbbr = blockIdx.x >= nb;
    int j = isAbbr ? (blockIdx.x - nb) : blockIdx.x;
    const void* tbl = isAbbr ? abbr : punct;
    uint32_t* out   = isAbbr ? bmA : bmP;
    int i = j * 256 + threadIdx.x;
    bool bit = (i < VV) ? lut(tbl, flag, i) : false;
    unsigned long long bal = __ballot(bit);
    if ((threadIdx.x & 63) == 0) {
        *(unsigned long long*)&out[i >> 5] = bal;
    }
}

// ---------------------------------------------------------------------------
// mono_kernel: natural bits + scan + fill in ONE dispatch.  512 blocks =
// 8 per row x 1024 threads (16 waves), 2 blocks/CU.
//  Phase 1: thread computes 8 consecutive tokens' natural/real bits (two int4
//    id loads; bitmap bit tests, L1-hot).  Bits -> LDS bytes; 128 threads
//    assemble 64-bit words with single ds_read_b64 (byte order = bit order).
//    natural[t] = real && ((punct[id] && !(t>0 && abbr[prev])) || t==last_real)
//    t==last_real is local (real prefix): real[t] && (t==T-1 || !real[t+1]).
//  Phase 2 (wave 0): word-parallel fire scan (verified r4/r6 code):
//    fire[t] = real[t] && (natural[t] || t === prevNat(t) (mod 32));
//    prevNat carries = exclusive MAX-scan of per-word last-natural positions;
//    per-word fire bits via segment walk; compaction via exclusive ADD-scan.
//  Phase 3: all 16 waves write this block's 1024-phrase slice:
//    mask(0/1) | token_idx | end_pos (int32), coalesced int4 stores.
// ---------------------------------------------------------------------------
__global__ __launch_bounds__(1024) void mono_kernel(
        const int* __restrict__ ids,
        const uint32_t* __restrict__ bmP,
        const uint32_t* __restrict__ bmA,
        int* __restrict__ out) {
    __shared__ unsigned long long sNat[128], sReal[128];
    __shared__ uint8_t sBN[1024], sBR[1024];
    __shared__ int sFires[TT];
    __shared__ int sNf;

    int b     = blockIdx.x >> 3;      // row
    int slice = blockIdx.x & 7;       // 1024-phrase slice within row
    int tid   = threadIdx.x;
    int wave  = tid >> 6, lane = tid & 63;

    // Phase 1: 8 tokens per thread
    const int* rowIds = ids + b * TT;
    int base = tid * 8;
    int4 va = *(const int4*)(rowIds + base);
    int4 vc = *(const int4*)(rowIds + base + 4);
    int id[9];
    id[0]=va.x; id[1]=va.y; id[2]=va.z; id[3]=va.w;
    id[4]=vc.x; id[5]=vc.y; id[6]=vc.z; id[7]=vc.w;
    id[8] = (tid < 1023) ? rowIds[base + 8] : 0;     // unused for t=TT-1
    int prev = (tid > 0) ? rowIds[base - 1] : 0;     // unused for t=0
    uint32_t nbits = 0, rbits = 0;
#pragma unroll
    for (int j = 0; j < 8; ++j) {
        int idj = id[j];
        bool real = (idj != 0);
        bool isLR = real && ((base + j == TT - 1) || (id[j + 1] == 0));
        bool e = false;
        if (real && ((bmP[idj >> 5] >> (idj & 31)) & 1u)) {
            int pid = j ? id[j - 1] : prev;
            e = (base + j == 0) ? true : !((bmA[pid >> 5] >> (pid & 31)) & 1u);
        }
        bool nat = real && (e || isLR);
        nbits |= (uint32_t)nat  << j;
        rbits |= (uint32_t)real << j;
    }
    sBN[tid] = (uint8_t)nbits;
    sBR[tid] = (uint8_t)rbits;
    __syncthreads();
    if (tid < 128) {
        sNat[tid]  = *(const unsigned long long*)&sBN[tid * 8];
        sReal[tid] = *(const unsigned long long*)&sBR[tid * 8];
    }
    __syncthreads();

    // Phase 2: wave 0 word-parallel scan -> sFires / sNf
    if (wave == 0) {
        unsigned long long nA = sNat[lane],  nB = sNat[lane + 64];
        unsigned long long rA = sReal[lane], rB = sReal[lane + 64];
        int lnA = nA ? lane * 64 + 63 - __clzll(nA) : -1;
        int lnB = nB ? (lane + 64) * 64 + 63 - __clzll(nB) : -1;
        int sA = lnA;
        for (int d = 1; d < 64; d <<= 1) { int v = __shfl_up(sA, d); if (lane >= d) sA = max(sA, v); }
        int exA = __shfl_up(sA, 1); if (lane == 0) exA = -1;
        int totA = __shfl(sA, 63);
        int sB = lnB;
        for (int d = 1; d < 64; d <<= 1) { int v = __shfl_up(sB, d); if (lane >= d) sB = max(sB, v); }
        int exB = __shfl_up(sB, 1); if (lane == 0) exB = -1;
        exB = max(exB, totA);

        auto fireWord = [&](unsigned long long nw, unsigned long long rw,
                            int widx, int carry) -> unsigned long long {
            long long wbase = (long long)widx * 64;
            unsigned long long fire = 0, rem = nw;
            long long cur = carry;
            while (true) {
                int nxt = rem ? (__ffsll(rem) - 1) : 64;
                int r = (int)(((cur - wbase) % 32 + 32) % 32);
                unsigned long long pat = (1ULL << r) | (1ULL << (r + 32));
                int s = (int)(cur - wbase + 1); if (s < 0) s = 0;
                fire |= pat & bitsBelow(nxt) & ~bitsBelow(s);
                if (!rem) break;
                fire |= 1ULL << nxt;
                cur = wbase + nxt;
                rem &= rem - 1;
            }
            return fire & rw;
        };
        unsigned long long fA = fireWord(nA, rA, lane, exA);
        unsigned long long fB = fireWord(nB, rB, lane + 64, exB);
        int pcA = __popcll(fA), pcB = __popcll(fB);
        int iA = pcA;
        for (int d = 1; d < 64; d <<= 1) { int v = __shfl_up(iA, d); if (lane >= d) iA += v; }
        int baseA = iA - pcA;
        int totPA = __shfl(iA, 63);
        int iB = pcB;
        for (int d = 1; d < 64; d <<= 1) { int v = __shfl_up(iB, d); if (lane >= d) iB += v; }
        int baseB = totPA + iB - pcB;
        int total = totPA + __shfl(iB, 63);
        unsigned long long f = fA; int idx = baseA;
        while (f) { int t = __ffsll(f) - 1; sFires[idx++] = lane * 64 + t; f &= f - 1; }
        f = fB; idx = baseB;
        while (f) { int t = __ffsll(f) - 1; sFires[idx++] = (lane + 64) * 64 + t; f &= f - 1; }
        if (lane == 0) sNf = total;
    }
    __syncthreads();

    // Phase 3: write this block's slice (1024 phrases x 32 slots x {mask,tok} + end)
    int nf = sNf;
    const long long MOFF = (long long)BB * TT * 32;
    int pbase = slice * 1024;
#pragma unroll
    for (int i = 0; i < 8; ++i) {
        int task = i * 1024 + tid;       // 0..8191
        int q  = task & 7;
        int lp = task >> 3;
        int gp = pbase + lp;
        int4 mv, tv;
        if (gp < nf) {
            int end   = sFires[gp];
            int start = (gp > 0) ? (sFires[gp - 1] + 1) : 0;
            int len   = end - start + 1;         // 1..32 guaranteed
            int s0 = q * 4;
            int* mp = (int*)&mv;
            int* tp = (int*)&tv;
#pragma unroll
            for (int j = 0; j < 4; ++j) {
                int s = s0 + j;
                bool m = s < len;
                mp[j] = m ? 1 : 0;
                tp[j] = m ? (start + s) : 0;
            }
        } else {
            mv = make_int4(0, 0, 0, 0);
            tv = mv;
        }
        long long bp = (long long)b * TT + gp;
        *(int4*)(out + bp * 32 + q * 4)        = mv;
        *(int4*)(out + MOFF + bp * 32 + q * 4) = tv;
    }
    {   // end_pos: one int per phrase
        int gp = pbase + tid;
        out[2 * MOFF + (long long)b * TT + gp] = (gp < nf) ? sFires[gp] : -1;
    }
}

extern "C" void kernel_launch(void* const* d_in, const int* in_sizes, int n_in,
                              void* d_out, int out_size, void* d_ws, size_t ws_size,
                              hipStream_t stream) {
    const int*  ids   = (const int*)d_in[0];
    const void* punct = d_in[1];
    const void* abbr  = d_in[2];
    char* ws = (char*)d_ws;
    uint32_t* bmP = (uint32_t*)(ws + WS_BMP);
    uint32_t* bmA = (uint32_t*)(ws + WS_BMA);
    int* out = (int*)d_out;

    const int nb = (VV + 255) / 256;                 // 197 blocks per table
    bitmap_kernel<<<2 * nb, 256, 0, stream>>>(punct, abbr, bmP, bmA);
    mono_kernel  <<<BB * 8, 1024, 0, stream>>>(ids, bmP, bmA, out);
}

// Round 8
// 31.287 us; speedup vs baseline: 1.1853x; 1.1853x over previous
//
#include <hip/hip_runtime.h>
#include <stdint.h>

// Problem constants (fixed by setup_inputs)
#define BB 64
#define TT 8192
// max_phrase_len = 32, pad_token_id = 0 (hardcoded)

// Workspace layout (byte offsets)
#define WS_PAIR   4096                 // ulonglong2[BB*128]  {nat, real} per 64-token word

#define MOFF ((long long)BB * TT * 32) // ints in mask (= ints in tok)

__device__ __forceinline__ unsigned long long bitsBelow(int e) {  // bits 0..e-1, e in [0,64]
    return (e >= 64) ? ~0ULL : ((1ULL << e) - 1ULL);
}

__device__ __forceinline__ bool lut(const void* tbl, int flag, int idx) {
    if (flag == 2) return ((const float*)tbl)[idx]   != 0.0f;
    if (flag == 1) return ((const uint8_t*)tbl)[idx] != 0;
    return ((const int*)tbl)[idx] != 0;
}

// ---------------------------------------------------------------------------
// bg_kernel: fuses the data-INDEPENDENT background output fill (mask=0, tok=0,
// end=-1 -- correct for ~95% of phrase slots since nf << 8192) with the
// per-token natural/real bit computation.  The ~3us of gather/ballot compute
// hides under ~20us of streaming background stores (write-bound either way).
// 2048 blocks x 256 threads.
//  - dtype probe first (has its own barriers; before stores are issued so the
//    barrier's vmcnt(0) drain doesn't serialize store completion w/ compute)
//  - background stores: 16 int4 zeros (mask+tok share) + 1 int -1 (end share)
//  - natural bits (verified r6 code):
//      natural[t] = real && ((punct[id] && !(t>0 && abbr[prev])) || t==last_real)
//      t==last_real local (real prefix): real[t] && (t==T-1 || !real[t+1])
//    ballot-packed {nat,real} -> pairW.
// ---------------------------------------------------------------------------
__global__ __launch_bounds__(256) void bg_kernel(
        const int* __restrict__ ids,
        const void* __restrict__ punct,
        const void* __restrict__ abbr,
        ulonglong2* __restrict__ pairW,
        int* __restrict__ out) {
    __shared__ int sFlag;
    if (threadIdx.x == 0) sFlag = 0;
    __syncthreads();
    {   // probe first 1024 int32 words (4KB; in-bounds for all 3 layouts)
        const uint32_t* w = (const uint32_t*)punct;
        bool byteGT1 = false, wordGT1 = false;
#pragma unroll
        for (int j = 0; j < 4; ++j) {
            uint32_t x = w[threadIdx.x * 4 + j];
            byteGT1 |= (x & 0xFEFEFEFEu) != 0u;   // f32: 1.0f has high bytes set
            wordGT1 |= (x > 1u);                  // uint8: packed bools > 1
        }
        int local = (byteGT1 ? 2 : 0) | (wordGT1 ? 1 : 0);
        if (local) atomicOr(&sFlag, local);
    }
    __syncthreads();
    int fl = sFlag;
    int flag = (fl & 2) ? 2 : (fl & 1);

    // background fill: this block's share.  mask+tok = 2*MOFF ints over 2048
    // blocks = 16384 ints/block = 16 int4/thread; end = 256 ints/block.
    {
        long long zbase = (long long)blockIdx.x * 16384;
        int4 z = make_int4(0, 0, 0, 0);
#pragma unroll
        for (int k = 0; k < 16; ++k) {
            *(int4*)(out + zbase + k * 1024 + threadIdx.x * 4) = z;
        }
        out[2 * MOFF + blockIdx.x * 256 + threadIdx.x] = -1;
    }

    // natural/real bits (overlaps with store drain; no barrier in between)
    int g = blockIdx.x * 256 + threadIdx.x;   // g = b*TT + t
    int t = g & (TT - 1);
    int id = ids[g];
    bool real = (id != 0);
    bool isLR = real && ((t == TT - 1) || (ids[g + 1] == 0));
    bool e = false;
    if (real) {
        bool pu = lut(punct, flag, id);
        if (pu) {                             // abbr gather predicated (~5%)
            bool pa = (t > 0) ? lut(abbr, flag, ids[g - 1]) : false;
            e = !pa;
        }
    }
    bool natural = real && (e || isLR);
    unsigned long long nb = __ballot(natural);
    unsigned long long rb = __ballot(real);
    if ((threadIdx.x & 63) == 0) {
        pairW[g >> 6] = make_ulonglong2(nb, rb);   // word = b*128 + (t>>6)
    }
}

// ---------------------------------------------------------------------------
// sparse_kernel: 64 blocks (1/row) x 1024 threads.
//  Prologue (wave 0): verified word-parallel fire scan over the row's 128
//  {nat,real} words.  Identity:
//    fire[t] = real[t] && (natural[t] || t === prevNat(t) (mod 32))
//  (init -1 behaves as position -1 => forced at t%32==31).  prevNat carries =
//  exclusive MAX-scan of per-word last-natural positions; per-word fire bits
//  via segment walk; compaction via exclusive ADD-scan.  Fire list -> LDS.
//  Main: only tasks t < nf*8 write (quad q of phrase p); everything else was
//  already correct from bg_kernel's background fill.
// ---------------------------------------------------------------------------
__global__ __launch_bounds__(1024) void sparse_kernel(
        const ulonglong2* __restrict__ pairW,
        int* __restrict__ out) {
    __shared__ int sFires[TT];
    __shared__ int sNf;

    int b    = blockIdx.x;
    int tid  = threadIdx.x;
    int wave = tid >> 6, lane = tid & 63;

    if (wave == 0) {
        ulonglong2 pA = pairW[b * 128 + lane];
        ulonglong2 pB = pairW[b * 128 + 64 + lane];
        unsigned long long nA = pA.x, rA = pA.y;
        unsigned long long nB = pB.x, rB = pB.y;
        int lnA = nA ? lane * 64 + 63 - __clzll(nA) : -1;
        int lnB = nB ? (lane + 64) * 64 + 63 - __clzll(nB) : -1;
        int sA = lnA;
        for (int d = 1; d < 64; d <<= 1) { int v = __shfl_up(sA, d); if (lane >= d) sA = max(sA, v); }
        int exA = __shfl_up(sA, 1); if (lane == 0) exA = -1;
        int totA = __shfl(sA, 63);
        int sB = lnB;
        for (int d = 1; d < 64; d <<= 1) { int v = __shfl_up(sB, d); if (lane >= d) sB = max(sB, v); }
        int exB = __shfl_up(sB, 1); if (lane == 0) exB = -1;
        exB = max(exB, totA);

        auto fireWord = [&](unsigned long long nw, unsigned long long rw,
                            int widx, int carry) -> unsigned long long {
            long long wbase = (long long)widx * 64;
            unsigned long long fire = 0, rem = nw;
            long long cur = carry;
            while (true) {
                int nxt = rem ? (__ffsll(rem) - 1) : 64;
                int r = (int)(((cur - wbase) % 32 + 32) % 32);
                unsigned long long pat = (1ULL << r) | (1ULL << (r + 32));
                int s = (int)(cur - wbase + 1); if (s < 0) s = 0;
                fire |= pat & bitsBelow(nxt) & ~bitsBelow(s);
                if (!rem) break;
                fire |= 1ULL << nxt;
                cur = wbase + nxt;
                rem &= rem - 1;
            }
            return fire & rw;
        };
        unsigned long long fA = fireWord(nA, rA, lane, exA);
        unsigned long long fB = fireWord(nB, rB, lane + 64, exB);
        int pcA = __popcll(fA), pcB = __popcll(fB);
        int iA = pcA;
        for (int d = 1; d < 64; d <<= 1) { int v = __shfl_up(iA, d); if (lane >= d) iA += v; }
        int baseA = iA - pcA;
        int totPA = __shfl(iA, 63);
        int iB = pcB;
        for (int d = 1; d < 64; d <<= 1) { int v = __shfl_up(iB, d); if (lane >= d) iB += v; }
        int baseB = totPA + iB - pcB;
        int total = totPA + __shfl(iB, 63);
        unsigned long long f = fA; int idx = baseA;
        while (f) { int t = __ffsll(f) - 1; sFires[idx++] = lane * 64 + t; f &= f - 1; }
        f = fB; idx = baseB;
        while (f) { int t = __ffsll(f) - 1; sFires[idx++] = (lane + 64) * 64 + t; f &= f - 1; }
        if (lane == 0) sNf = total;
    }
    __syncthreads();

    int nf = sNf;
    int ntask = nf * 8;                       // 8 quads per real phrase
    for (int task = tid; task < ntask; task += 1024) {
        int q = task & 7;
        int p = task >> 3;
        int end   = sFires[p];
        int start = (p > 0) ? (sFires[p - 1] + 1) : 0;
        int len   = end - start + 1;          // 1..32 guaranteed
        int s0 = q * 4;
        int4 mv, tv;
        int* mp = (int*)&mv;
        int* tp = (int*)&tv;
#pragma unroll
        for (int j = 0; j < 4; ++j) {
            int s = s0 + j;
            bool m = s < len;
            mp[j] = m ? 1 : 0;
            tp[j] = m ? (start + s) : 0;
        }
        long long bp = (long long)b * TT + p;
        *(int4*)(out + bp * 32 + q * 4)        = mv;
        *(int4*)(out + MOFF + bp * 32 + q * 4) = tv;
        if (q == 0) out[2 * MOFF + bp] = end;
    }
}

extern "C" void kernel_launch(void* const* d_in, const int* in_sizes, int n_in,
                              void* d_out, int out_size, void* d_ws, size_t ws_size,
                              hipStream_t stream) {
    const int*  ids   = (const int*)d_in[0];
    const void* punct = d_in[1];
    const void* abbr  = d_in[2];
    char* ws = (char*)d_ws;
    ulonglong2* pairW = (ulonglong2*)(ws + WS_PAIR);
    int* out = (int*)d_out;

    bg_kernel    <<<(BB * TT) / 256, 256, 0, stream>>>(ids, punct, abbr, pairW, out);
    sparse_kernel<<<BB, 1024, 0, stream>>>(pairW, out);
}